// Round 2
// baseline (714.384 us; speedup 1.0000x reference)
//
#include <hip/hip_runtime.h>

// VEConv: E=800000 edges, N=50000 nodes, RBF=100, D=64. E % 64 == 0.
// Fully barrier-free design: each wave owns 16 edges; MFMA B-fragments are
// loaded per-lane directly from global (8 contiguous f32 -> bf16x8), and the
// epilogue runs from the accumulator registers (lane (g,l15) holds 16 of the
// 64 d-values of edge l15). Only an 8 KiB per-wave LDS buffer remains for the
// GEMM1->GEMM2 softplus transpose.
#define RBF_DIM 100

typedef __attribute__((ext_vector_type(8))) short bf16x8;
typedef __attribute__((ext_vector_type(4))) float f32x4;

__device__ __forceinline__ unsigned short f2bf(float f) {
    union { float f; unsigned int u; } v; v.f = f;
    unsigned int r = (v.u + 0x7FFFu + ((v.u >> 16) & 1u)) >> 16;
    return (unsigned short)r;
}

__device__ __forceinline__ bf16x8 cvt8(f32x4 a, f32x4 b) {
    bf16x8 r;
    r[0] = (short)f2bf(a[0]); r[1] = (short)f2bf(a[1]);
    r[2] = (short)f2bf(a[2]); r[3] = (short)f2bf(a[3]);
    r[4] = (short)f2bf(b[0]); r[5] = (short)f2bf(b[1]);
    r[6] = (short)f2bf(b[2]); r[7] = (short)f2bf(b[3]);
    return r;
}

// ---- pre-kernel: transposed bf16 weights into ws ----
// ws layout (ushort): [0,8192) W1T[64][128]  (k=100 -> b1, k>100 -> 0)
//                     [8192,12288) W2T[64][64]
//                     [12288,16384) W3T[64][64]
__global__ void prep_weights(const float* __restrict__ W1, const float* __restrict__ b1,
                             const float* __restrict__ W2, const float* __restrict__ W3,
                             unsigned short* __restrict__ ws) {
    int t = threadIdx.x;
    for (int idx = t; idx < 64 * 128; idx += 256) {
        int o = idx >> 7, k = idx & 127;
        float v = (k < RBF_DIM) ? W1[k * 64 + o] : ((k == RBF_DIM) ? b1[o] : 0.0f);
        ws[idx] = f2bf(v);
    }
    for (int idx = t; idx < 64 * 64; idx += 256) {
        int o = idx >> 6, k = idx & 63;
        ws[8192 + idx]  = f2bf(W2[k * 64 + o]);
        ws[12288 + idx] = f2bf(W3[k * 64 + o]);
    }
}

// ---- main fused kernel: 64 edges/block, 4 independent waves x 16 edges ----
__global__ __launch_bounds__(256, 4)
void veconv_main(const float* __restrict__ rbf, const float* __restrict__ edge_f,
                 const float* __restrict__ node,
                 const float* __restrict__ b2, const float* __restrict__ b3,
                 const int* __restrict__ src, const int* __restrict__ dst,
                 const unsigned short* __restrict__ wsw,
                 float* __restrict__ out) {
    __shared__ unsigned short sp_lds[4 * 16 * 64]; // per-wave softplus transpose buf

    const int tid = threadIdx.x;
    const int lane = tid & 63, wid = tid >> 6;
    const int l15 = lane & 15, g = lane >> 4;
    const int eg = blockIdx.x * 64 + wid * 16 + l15;   // this lane's edge (B col)
    const int swz = (l15 & 7) << 3;

    // ---- weight A-fragments (lane m = l15 -> out row 16*t4+l15, k slice 8*g) ----
    bf16x8 w1f[4][4], w2f[4][2], w3f[4][2];
    for (int t4 = 0; t4 < 4; ++t4) {
        for (int ks = 0; ks < 4; ++ks)
            w1f[t4][ks] = *(const bf16x8*)(wsw + (16 * t4 + l15) * 128 + 32 * ks + 8 * g);
        for (int ks = 0; ks < 2; ++ks) {
            w2f[t4][ks] = *(const bf16x8*)(wsw + 8192  + (16 * t4 + l15) * 64 + 32 * ks + 8 * g);
            w3f[t4][ks] = *(const bf16x8*)(wsw + 12288 + (16 * t4 + l15) * 64 + 32 * ks + 8 * g);
        }
    }

    // ---- GEMM1: D1[out][e] = W1T @ rbf^T, B-frags straight from global ----
    const float* rrow = rbf + (long)eg * RBF_DIM;
    f32x4 acc1[4];
    for (int t4 = 0; t4 < 4; ++t4) acc1[t4] = (f32x4){0.f, 0.f, 0.f, 0.f};
    for (int ks = 0; ks < 3; ++ks) {
        f32x4 a = *(const f32x4*)(rrow + 32 * ks + 8 * g);
        f32x4 b = *(const f32x4*)(rrow + 32 * ks + 8 * g + 4);
        bf16x8 bf = cvt8(a, b);
        for (int t4 = 0; t4 < 4; ++t4)
            acc1[t4] = __builtin_amdgcn_mfma_f32_16x16x32_bf16(w1f[t4][ks], bf, acc1[t4], 0, 0, 0);
    }
    {   // ks=3: k=96..127 -> only g==0 has real data (96..99), k=100 is the bias-1.0 col
        bf16x8 bf = (bf16x8){0, 0, 0, 0, 0, 0, 0, 0};
        if (g == 0) {
            f32x4 a = *(const f32x4*)(rrow + 96);
            bf[0] = (short)f2bf(a[0]); bf[1] = (short)f2bf(a[1]);
            bf[2] = (short)f2bf(a[2]); bf[3] = (short)f2bf(a[3]);
            bf[4] = (short)0x3F80; // 1.0 -> picks up b1 row of W1T
        }
        for (int t4 = 0; t4 < 4; ++t4)
            acc1[t4] = __builtin_amdgcn_mfma_f32_16x16x32_bf16(w1f[t4][3], bf, acc1[t4], 0, 0, 0);
    }

    // ---- softplus(beta=0.5, thr=14) in-register; sp[e][k] bf16 swizzled ----
    // C-layout: lane (g,l15) holds col e=l15, rows d = 16*t4 + 4*g + r
    for (int t4 = 0; t4 < 4; ++t4) {
        float spv[4];
        for (int r = 0; r < 4; ++r) {
            float x = acc1[t4][r];
            float bx = 0.5f * x;
            float s = 2.0f * __logf(1.0f + __expf(bx));
            spv[r] = (bx > 14.0f) ? x : s;
        }
        unsigned int p0 = (unsigned int)f2bf(spv[0]) | ((unsigned int)f2bf(spv[1]) << 16);
        unsigned int p1 = (unsigned int)f2bf(spv[2]) | ((unsigned int)f2bf(spv[3]) << 16);
        int el = (wid * 16 + l15) * 64 + ((16 * t4 + 4 * g) ^ swz);
        *(uint2*)&sp_lds[el] = make_uint2(p0, p1);
    }
    // intra-wave LDS dep only (each wave reads its own region) -> no barrier

    // ---- GEMM2: h = W2T @ sp^T; GEMM3: en = W3T @ edge_f^T ----
    const float* erow = edge_f + (long)eg * 64;
    f32x4 acc2[4], acc3[4];
    for (int t4 = 0; t4 < 4; ++t4) {
        acc2[t4] = (f32x4){0.f, 0.f, 0.f, 0.f};
        acc3[t4] = (f32x4){0.f, 0.f, 0.f, 0.f};
    }
    for (int ks = 0; ks < 2; ++ks) {
        bf16x8 bsp = *(const bf16x8*)&sp_lds[(wid * 16 + l15) * 64 + ((32 * ks + 8 * g) ^ swz)];
        f32x4 a = *(const f32x4*)(erow + 32 * ks + 8 * g);
        f32x4 b = *(const f32x4*)(erow + 32 * ks + 8 * g + 4);
        bf16x8 bef = cvt8(a, b);
        for (int t4 = 0; t4 < 4; ++t4) {
            acc2[t4] = __builtin_amdgcn_mfma_f32_16x16x32_bf16(w2f[t4][ks], bsp, acc2[t4], 0, 0, 0);
            acc3[t4] = __builtin_amdgcn_mfma_f32_16x16x32_bf16(w3f[t4][ks], bef, acc3[t4], 0, 0, 0);
        }
    }

    // ---- epilogue, all from registers: lane (g,l15) owns edge eg's d = 16*t4+4*g+r ----
    const int s = src[eg], d = dst[eg];
    const float* nrow = node + (long)s * 64;
    float* orow = out + (long)d * 64;
    for (int t4 = 0; t4 < 4; ++t4) {
        const int dd = 16 * t4 + 4 * g;
        f32x4 nd = *(const f32x4*)(nrow + dd);
        f32x4 c2 = *(const f32x4*)(b2 + dd);
        f32x4 c3 = *(const f32x4*)(b3 + dd);
        for (int r = 0; r < 4; ++r) {
            float msg = nd[r] * (acc2[t4][r] + c2[r]) + (acc3[t4][r] + c3[r]);
            atomicAdd(&orow[dd + r], msg);
        }
    }
}

extern "C" void kernel_launch(void* const* d_in, const int* in_sizes, int n_in,
                              void* d_out, int out_size, void* d_ws, size_t ws_size,
                              hipStream_t stream) {
    const float* rbf    = (const float*)d_in[0];
    const float* edge_f = (const float*)d_in[1];
    const float* node   = (const float*)d_in[2];
    const float* W1     = (const float*)d_in[3];
    const float* b1     = (const float*)d_in[4];
    const float* W2     = (const float*)d_in[5];
    const float* b2     = (const float*)d_in[6];
    const float* W3     = (const float*)d_in[7];
    const float* b3     = (const float*)d_in[8];
    const int*   src    = (const int*)d_in[9];
    const int*   dst    = (const int*)d_in[10];
    float* out = (float*)d_out;
    unsigned short* ws = (unsigned short*)d_ws;

    const int E = in_sizes[9];              // 800000, divisible by 64

    hipMemsetAsync(d_out, 0, (size_t)out_size * sizeof(float), stream);
    prep_weights<<<1, 256, 0, stream>>>(W1, b1, W2, W3, ws);
    veconv_main<<<E / 64, 256, 0, stream>>>(rbf, edge_f, node, b2, b3, src, dst, ws, out);
}

// Round 3
// 321.361 us; speedup vs baseline: 2.2230x; 2.2230x over previous
//
#include <hip/hip_runtime.h>

// VEConv: E=800000 edges, N=50000 nodes, RBF=100, D=64. E % 64 == 0.
// Barrier-free: each wave owns 16 edges. GEMM1 computes D1[d][e] (weights as
// A-operand); softplus transposes through an 8 KiB per-wave LDS buffer; GEMM2
// and GEMM3 swap MFMA operand order so D[e][d] comes out edge-major -> the
// epilogue does coalesced (contiguous-dim) node gathers and atomic scatters
// straight from the accumulators. No __syncthreads anywhere.
#define RBF_DIM 100

typedef __attribute__((ext_vector_type(8))) short bf16x8;
typedef __attribute__((ext_vector_type(4))) float f32x4;

__device__ __forceinline__ unsigned short f2bf(float f) {
    union { float f; unsigned int u; } v; v.f = f;
    unsigned int r = (v.u + 0x7FFFu + ((v.u >> 16) & 1u)) >> 16;
    return (unsigned short)r;
}

__device__ __forceinline__ bf16x8 cvt8(f32x4 a, f32x4 b) {
    bf16x8 r;
    r[0] = (short)f2bf(a[0]); r[1] = (short)f2bf(a[1]);
    r[2] = (short)f2bf(a[2]); r[3] = (short)f2bf(a[3]);
    r[4] = (short)f2bf(b[0]); r[5] = (short)f2bf(b[1]);
    r[6] = (short)f2bf(b[2]); r[7] = (short)f2bf(b[3]);
    return r;
}

// ---- pre-kernel: transposed bf16 weights into ws ----
// ws layout (ushort): [0,8192) W1T[64][128]  (k=100 -> b1, k>100 -> 0)
//                     [8192,12288) W2T[64][64]
//                     [12288,16384) W3T[64][64]
__global__ void prep_weights(const float* __restrict__ W1, const float* __restrict__ b1,
                             const float* __restrict__ W2, const float* __restrict__ W3,
                             unsigned short* __restrict__ ws) {
    int t = threadIdx.x;
    for (int idx = t; idx < 64 * 128; idx += 256) {
        int o = idx >> 7, k = idx & 127;
        float v = (k < RBF_DIM) ? W1[k * 64 + o] : ((k == RBF_DIM) ? b1[o] : 0.0f);
        ws[idx] = f2bf(v);
    }
    for (int idx = t; idx < 64 * 64; idx += 256) {
        int o = idx >> 6, k = idx & 63;
        ws[8192 + idx]  = f2bf(W2[k * 64 + o]);
        ws[12288 + idx] = f2bf(W3[k * 64 + o]);
    }
}

// ---- main fused kernel: 64 edges/block, 4 independent waves x 16 edges ----
__global__ __launch_bounds__(256, 4)
void veconv_main(const float* __restrict__ rbf, const float* __restrict__ edge_f,
                 const float* __restrict__ node,
                 const float* __restrict__ b2, const float* __restrict__ b3,
                 const int* __restrict__ src, const int* __restrict__ dst,
                 const unsigned short* __restrict__ wsw,
                 float* __restrict__ out) {
    __shared__ unsigned short sp_lds[4 * 16 * 64]; // per-wave softplus transpose buf

    const int tid = threadIdx.x;
    const int lane = tid & 63, wid = tid >> 6;
    const int l15 = lane & 15, g = lane >> 4;
    const int ew0 = blockIdx.x * 64 + wid * 16;        // this wave's first edge
    const int eg = ew0 + l15;                          // this lane's B-col edge
    const int swz = (l15 & 7) << 3;

    // src/dst for the 4 edges this lane owns in the epilogue (e_loc = 4g + r)
    int srcv[4], dstv[4];
    for (int r = 0; r < 4; ++r) {
        srcv[r] = src[ew0 + 4 * g + r];
        dstv[r] = dst[ew0 + 4 * g + r];
    }
    // biases for epilogue dims d = 16*t4 + l15
    float b2v[4], b3v[4];
    for (int t4 = 0; t4 < 4; ++t4) { b2v[t4] = b2[16 * t4 + l15]; b3v[t4] = b3[16 * t4 + l15]; }

    // ---- GEMM1: D1[d][e] = W1T @ rbf^T (weights = A, rbf rows = B, from global) ----
    const float* rrow = rbf + (long)eg * RBF_DIM;
    f32x4 acc1[4];
    for (int t4 = 0; t4 < 4; ++t4) acc1[t4] = (f32x4){0.f, 0.f, 0.f, 0.f};
    for (int ks = 0; ks < 3; ++ks) {
        f32x4 a = *(const f32x4*)(rrow + 32 * ks + 8 * g);
        f32x4 b = *(const f32x4*)(rrow + 32 * ks + 8 * g + 4);
        bf16x8 bf = cvt8(a, b);
        for (int t4 = 0; t4 < 4; ++t4) {
            bf16x8 w = *(const bf16x8*)(wsw + (16 * t4 + l15) * 128 + 32 * ks + 8 * g);
            acc1[t4] = __builtin_amdgcn_mfma_f32_16x16x32_bf16(w, bf, acc1[t4], 0, 0, 0);
        }
    }
    {   // ks=3: k=96..127 -> only g==0 has real data (96..99), k=100 = bias-1.0 col
        bf16x8 bf = (bf16x8){0, 0, 0, 0, 0, 0, 0, 0};
        if (g == 0) {
            f32x4 a = *(const f32x4*)(rrow + 96);
            bf[0] = (short)f2bf(a[0]); bf[1] = (short)f2bf(a[1]);
            bf[2] = (short)f2bf(a[2]); bf[3] = (short)f2bf(a[3]);
            bf[4] = (short)0x3F80; // 1.0 -> picks up b1 row of W1T
        }
        for (int t4 = 0; t4 < 4; ++t4) {
            bf16x8 w = *(const bf16x8*)(wsw + (16 * t4 + l15) * 128 + 96 + 8 * g);
            acc1[t4] = __builtin_amdgcn_mfma_f32_16x16x32_bf16(w, bf, acc1[t4], 0, 0, 0);
        }
    }

    // ---- softplus(beta=0.5, thr=14) in-register; sp[e][k] bf16 swizzled ----
    // D1 layout: lane (g,l15) holds col e=l15, rows d = 16*t4 + 4*g + r
    for (int t4 = 0; t4 < 4; ++t4) {
        float spv[4];
        for (int r = 0; r < 4; ++r) {
            float x = acc1[t4][r];
            float bx = 0.5f * x;
            float s = 2.0f * __logf(1.0f + __expf(bx));
            spv[r] = (bx > 14.0f) ? x : s;
        }
        unsigned int p0 = (unsigned int)f2bf(spv[0]) | ((unsigned int)f2bf(spv[1]) << 16);
        unsigned int p1 = (unsigned int)f2bf(spv[2]) | ((unsigned int)f2bf(spv[3]) << 16);
        int el = (wid * 16 + l15) * 64 + ((16 * t4 + 4 * g) ^ swz);
        *(uint2*)&sp_lds[el] = make_uint2(p0, p1);
    }
    // intra-wave LDS dep only (each wave reads its own region) -> no barrier

    // ---- GEMM2/GEMM3 with SWAPPED operands: D[e][d] = sp/ef (A) @ W (B) ----
    const float* erow = edge_f + (long)eg * 64;
    f32x4 acc2[4], acc3[4];
    for (int t4 = 0; t4 < 4; ++t4) {
        acc2[t4] = (f32x4){0.f, 0.f, 0.f, 0.f};
        acc3[t4] = (f32x4){0.f, 0.f, 0.f, 0.f};
    }
    for (int ks = 0; ks < 2; ++ks) {
        bf16x8 asp = *(const bf16x8*)&sp_lds[(wid * 16 + l15) * 64 + ((32 * ks + 8 * g) ^ swz)];
        f32x4 a = *(const f32x4*)(erow + 32 * ks + 8 * g);
        f32x4 b = *(const f32x4*)(erow + 32 * ks + 8 * g + 4);
        bf16x8 aef = cvt8(a, b);
        for (int t4 = 0; t4 < 4; ++t4) {
            bf16x8 w2 = *(const bf16x8*)(wsw + 8192  + (16 * t4 + l15) * 64 + 32 * ks + 8 * g);
            bf16x8 w3 = *(const bf16x8*)(wsw + 12288 + (16 * t4 + l15) * 64 + 32 * ks + 8 * g);
            acc2[t4] = __builtin_amdgcn_mfma_f32_16x16x32_bf16(asp, w2, acc2[t4], 0, 0, 0);
            acc3[t4] = __builtin_amdgcn_mfma_f32_16x16x32_bf16(aef, w3, acc3[t4], 0, 0, 0);
        }
    }
    // acc2/acc3 layout: lane (g,l15) holds edge e_loc = 4g + r, dim d = 16*t4 + l15

    // ---- epilogue: coalesced node gather + contiguous-dim atomic scatter ----
    float nd[4][4];
    for (int r = 0; r < 4; ++r)
        for (int t4 = 0; t4 < 4; ++t4)
            nd[r][t4] = node[(long)srcv[r] * 64 + 16 * t4 + l15];
    for (int r = 0; r < 4; ++r) {
        float* orow = out + (long)dstv[r] * 64 + l15;
        for (int t4 = 0; t4 < 4; ++t4) {
            float msg = nd[r][t4] * (acc2[t4][r] + b2v[t4]) + (acc3[t4][r] + b3v[t4]);
            atomicAdd(&orow[16 * t4], msg);
        }
    }
}

extern "C" void kernel_launch(void* const* d_in, const int* in_sizes, int n_in,
                              void* d_out, int out_size, void* d_ws, size_t ws_size,
                              hipStream_t stream) {
    const float* rbf    = (const float*)d_in[0];
    const float* edge_f = (const float*)d_in[1];
    const float* node   = (const float*)d_in[2];
    const float* W1     = (const float*)d_in[3];
    const float* b1     = (const float*)d_in[4];
    const float* W2     = (const float*)d_in[5];
    const float* b2     = (const float*)d_in[6];
    const float* W3     = (const float*)d_in[7];
    const float* b3     = (const float*)d_in[8];
    const int*   src    = (const int*)d_in[9];
    const int*   dst    = (const int*)d_in[10];
    float* out = (float*)d_out;
    unsigned short* ws = (unsigned short*)d_ws;

    const int E = in_sizes[9];              // 800000, divisible by 64

    hipMemsetAsync(d_out, 0, (size_t)out_size * sizeof(float), stream);
    prep_weights<<<1, 256, 0, stream>>>(W1, b1, W2, W3, ws);
    veconv_main<<<E / 64, 256, 0, stream>>>(rbf, edge_f, node, b2, b3, src, dst, ws, out);
}